// Round 1
// baseline (258.149 us; speedup 1.0000x reference)
//
#include <hip/hip_runtime.h>
#include <stdint.h>

// Problem constants
#define T_DIM 512
#define B_DIM 128
#define DIN   512
#define H_DIM 1024
#define M_DIM (T_DIM * B_DIM)          // 65536
#define OUT_ELEMS (M_DIM * H_DIM)      // 67108864

typedef __attribute__((ext_vector_type(8))) short bf16x8;
typedef __attribute__((ext_vector_type(4))) float f32x4;
typedef unsigned short u16;

static __device__ __forceinline__ u16 f2bf(float f) {
    union { float f; uint32_t u; } v; v.f = f;
    uint32_t u = v.u;
    // round-to-nearest-even bf16
    uint32_t r = (u + 0x7FFFu + ((u >> 16) & 1u)) >> 16;
    return (u16)r;
}

// ---------------------------------------------------------------------------
// Kernel 1: convert W_in, W_h, hidden to bf16 in ws; copy hidden to d_out tail
// ---------------------------------------------------------------------------
__global__ __launch_bounds__(256) void k_convert(
    const float* __restrict__ W_in, const float* __restrict__ W_h,
    const float* __restrict__ hidden,
    u16* __restrict__ Win_bf, u16* __restrict__ Wh_bf, u16* __restrict__ hid_bf,
    float* __restrict__ out_hidden)
{
    int idx = blockIdx.x * 256 + threadIdx.x;   // 0 .. 1703935
    if (idx < 524288) {
        Win_bf[idx] = f2bf(W_in[idx]);
    } else if (idx < 1572864) {
        int i = idx - 524288;
        Wh_bf[i] = f2bf(W_h[i]);
    } else {
        int i = idx - 1572864;                  // 0 .. 131071
        float h = hidden[i];
        hid_bf[i] = f2bf(h);
        out_hidden[i] = h;                      // second tuple output: hidden
    }
}

// ---------------------------------------------------------------------------
// Kernel 2: bias2[b][h] = hidden @ W_h^T + b_h + b_in   (128 x 1024, K=1024)
// MFMA 16x16x32 bf16, 64x64 block tile, 4 waves of 32x32.
// ---------------------------------------------------------------------------
__global__ __launch_bounds__(256, 2) void k_bias2(
    const u16* __restrict__ hid_bf, const u16* __restrict__ Wh_bf,
    const float* __restrict__ b_in, const float* __restrict__ b_h,
    float* __restrict__ bias2)
{
    __shared__ alignas(16) char lds[16384];     // A: [0,8192) B: [8192,16384)
    const int tid = threadIdx.x;
    const int mt = blockIdx.x & 1, nt = blockIdx.x >> 1;   // 2 x 16 tiles
    const int m0 = mt * 64, n0 = nt * 64;
    const int l = tid & 63, w = tid >> 6;
    const int wm = w >> 1, wn = w & 1;
    const int r = l & 15, q = l >> 4;

    f32x4 acc[2][2] = {};

    for (int kb = 0; kb < 1024; kb += 64) {
        __syncthreads();
        #pragma unroll
        for (int i = 0; i < 2; ++i) {
            int idx = tid + i * 256;            // 0..511 : 64 rows x 8 chunks
            int row = idx >> 3, koff = (idx & 7) * 8;
            int off = (row * 128 + koff * 2) ^ ((row & 7) << 4);
            bf16x8 av = *reinterpret_cast<const bf16x8*>(&hid_bf[(m0 + row) * 1024 + kb + koff]);
            *reinterpret_cast<bf16x8*>(&lds[off]) = av;
            bf16x8 bv = *reinterpret_cast<const bf16x8*>(&Wh_bf[(n0 + row) * 1024 + kb + koff]);
            *reinterpret_cast<bf16x8*>(&lds[8192 + off]) = bv;
        }
        __syncthreads();
        #pragma unroll
        for (int kk = 0; kk < 2; ++kk) {
            bf16x8 a[2], b[2];
            #pragma unroll
            for (int mi = 0; mi < 2; ++mi) {
                int row = wm * 32 + mi * 16 + r;
                int off = (row * 128 + kk * 64 + q * 16) ^ ((row & 7) << 4);
                a[mi] = *reinterpret_cast<const bf16x8*>(&lds[off]);
            }
            #pragma unroll
            for (int ni = 0; ni < 2; ++ni) {
                int row = wn * 32 + ni * 16 + r;
                int off = 8192 + ((row * 128 + kk * 64 + q * 16) ^ ((row & 7) << 4));
                b[ni] = *reinterpret_cast<const bf16x8*>(&lds[off]);
            }
            #pragma unroll
            for (int mi = 0; mi < 2; ++mi)
                #pragma unroll
                for (int ni = 0; ni < 2; ++ni)
                    acc[mi][ni] = __builtin_amdgcn_mfma_f32_16x16x32_bf16(
                        a[mi], b[ni], acc[mi][ni], 0, 0, 0);
        }
    }
    #pragma unroll
    for (int mi = 0; mi < 2; ++mi)
        #pragma unroll
        for (int ni = 0; ni < 2; ++ni)
            #pragma unroll
            for (int reg = 0; reg < 4; ++reg) {
                int brow = m0 + wm * 32 + mi * 16 + q * 4 + reg;
                int col  = n0 + wn * 32 + ni * 16 + r;
                bias2[brow * 1024 + col] = acc[mi][ni][reg] + b_in[col] + b_h[col];
            }
}

// ---------------------------------------------------------------------------
// Kernel 3: main GEMM  out[m][n] = 0.9*hidden[b][n] + 0.1*relu(x@W_in^T + bias2)
// 128x128 tile, BK=64, 256 threads = 4 waves of 64x64 (4x4 16x16 frags).
// A (x) is f32 -> converted to bf16 in-register, XOR-swizzled LDS.
// ---------------------------------------------------------------------------
__global__ __launch_bounds__(256, 2) void k_main(
    const float* __restrict__ x,          // [65536][512] f32
    const u16*   __restrict__ Win_bf,     // [1024][512] bf16
    const float* __restrict__ bias2,      // [128][1024]
    const float* __restrict__ hidden,     // [128][1024]
    float* __restrict__ out)              // [65536][1024]
{
    __shared__ alignas(16) char lds[32768];   // A: [0,16384) B: [16384,32768)
    const int tid = threadIdx.x;
    const int bid = blockIdx.x;
    const int nt = bid & 7, mt = bid >> 3;    // 8 N-tiles adjacent -> L3 reuse of A
    const int m0 = mt * 128, n0 = nt * 128;
    const int l = tid & 63, w = tid >> 6;
    const int wm = w >> 1, wn = w & 1;        // 2x2 waves
    const int r = l & 15, q = l >> 4;

    f32x4 acc[4][4] = {};

    for (int kb = 0; kb < 512; kb += 64) {
        __syncthreads();
        // ---- stage A (128x64 f32 -> bf16) and B (128x64 bf16) ----
        #pragma unroll
        for (int i = 0; i < 4; ++i) {
            int idx = tid + i * 256;          // 0..1023 : 128 rows x 8 chunks
            int row = idx >> 3, koff = (idx & 7) * 8;
            int off = (row * 128 + koff * 2) ^ ((row & 7) << 4);
            const float* src = &x[(size_t)(m0 + row) * 512 + kb + koff];
            float4 v0 = *reinterpret_cast<const float4*>(src);
            float4 v1 = *reinterpret_cast<const float4*>(src + 4);
            union { bf16x8 v; u16 s[8]; } u;
            u.s[0] = f2bf(v0.x); u.s[1] = f2bf(v0.y);
            u.s[2] = f2bf(v0.z); u.s[3] = f2bf(v0.w);
            u.s[4] = f2bf(v1.x); u.s[5] = f2bf(v1.y);
            u.s[6] = f2bf(v1.z); u.s[7] = f2bf(v1.w);
            *reinterpret_cast<bf16x8*>(&lds[off]) = u.v;
            bf16x8 bv = *reinterpret_cast<const bf16x8*>(&Win_bf[(n0 + row) * 512 + kb + koff]);
            *reinterpret_cast<bf16x8*>(&lds[16384 + off]) = bv;
        }
        __syncthreads();
        // ---- compute: 2 x (4 A-frags, 4 B-frags, 16 MFMA) ----
        #pragma unroll
        for (int kk = 0; kk < 2; ++kk) {
            bf16x8 a[4], b[4];
            #pragma unroll
            for (int mi = 0; mi < 4; ++mi) {
                int row = wm * 64 + mi * 16 + r;
                int off = (row * 128 + kk * 64 + q * 16) ^ ((row & 7) << 4);
                a[mi] = *reinterpret_cast<const bf16x8*>(&lds[off]);
            }
            #pragma unroll
            for (int ni = 0; ni < 4; ++ni) {
                int row = wn * 64 + ni * 16 + r;
                int off = 16384 + ((row * 128 + kk * 64 + q * 16) ^ ((row & 7) << 4));
                b[ni] = *reinterpret_cast<const bf16x8*>(&lds[off]);
            }
            #pragma unroll
            for (int mi = 0; mi < 4; ++mi)
                #pragma unroll
                for (int ni = 0; ni < 4; ++ni)
                    acc[mi][ni] = __builtin_amdgcn_mfma_f32_16x16x32_bf16(
                        a[mi], b[ni], acc[mi][ni], 0, 0, 0);
        }
    }
    // ---- epilogue: out = 0.9*hidden + 0.1*relu(acc + bias2) ----
    #pragma unroll
    for (int mi = 0; mi < 4; ++mi) {
        #pragma unroll
        for (int reg = 0; reg < 4; ++reg) {
            int grow = m0 + wm * 64 + mi * 16 + q * 4 + reg;
            int b = grow & 127;               // m = t*128 + b
            #pragma unroll
            for (int ni = 0; ni < 4; ++ni) {
                int col = n0 + wn * 64 + ni * 16 + r;
                float pre = acc[mi][ni][reg] + bias2[b * 1024 + col];
                float val = 0.1f * fmaxf(pre, 0.0f) + 0.9f * hidden[b * 1024 + col];
                out[(size_t)grow * 1024 + col] = val;
            }
        }
    }
}

// ---------------------------------------------------------------------------
extern "C" void kernel_launch(void* const* d_in, const int* in_sizes, int n_in,
                              void* d_out, int out_size, void* d_ws, size_t ws_size,
                              hipStream_t stream) {
    const float* x      = (const float*)d_in[0];
    const float* hidden = (const float*)d_in[1];
    const float* W_in   = (const float*)d_in[2];
    const float* b_in   = (const float*)d_in[3];
    const float* W_h    = (const float*)d_in[4];
    const float* b_h    = (const float*)d_in[5];
    float* out = (float*)d_out;

    char* ws = (char*)d_ws;
    u16*   Win_bf = (u16*)  (ws + 0);          // 1 MiB
    u16*   Wh_bf  = (u16*)  (ws + 1048576);    // 2 MiB
    u16*   hid_bf = (u16*)  (ws + 3145728);    // 256 KiB
    float* bias2  = (float*)(ws + 3407872);    // 512 KiB

    float* out_hidden = out + OUT_ELEMS;       // tuple output 1: hidden

    k_convert<<<6656, 256, 0, stream>>>(W_in, W_h, hidden, Win_bf, Wh_bf, hid_bf, out_hidden);
    k_bias2<<<32, 256, 0, stream>>>(hid_bf, Wh_bf, b_in, b_h, bias2);
    k_main<<<4096, 256, 0, stream>>>(x, Win_bf, bias2, hidden, out);
}

// Round 2
// 203.087 us; speedup vs baseline: 1.2711x; 1.2711x over previous
//
#include <hip/hip_runtime.h>
#include <stdint.h>

// Problem constants
#define T_DIM 512
#define B_DIM 128
#define DIN   512
#define H_DIM 1024
#define M_DIM (T_DIM * B_DIM)          // 65536
#define OUT_ELEMS (M_DIM * H_DIM)      // 67108864

typedef __attribute__((ext_vector_type(8))) short bf16x8;
typedef __attribute__((ext_vector_type(4))) float f32x4;
typedef unsigned short u16;

static __device__ __forceinline__ u16 f2bf(float f) {
    union { float f; uint32_t u; } v; v.f = f;
    uint32_t u = v.u;
    uint32_t r = (u + 0x7FFFu + ((u >> 16) & 1u)) >> 16;   // RNE
    return (u16)r;
}

typedef const __attribute__((address_space(1))) void GASV;
typedef __attribute__((address_space(3))) void LASV;
static __device__ __forceinline__ void gload_lds16(const void* g, void* l) {
    __builtin_amdgcn_global_load_lds((GASV*)g, (LASV*)l, 16, 0, 0);
}

// ---------------------------------------------------------------------------
// Kernel 1: convert W_in, W_h, hidden to bf16 in ws; copy hidden to d_out tail
// ---------------------------------------------------------------------------
__global__ __launch_bounds__(256) void k_convert(
    const float* __restrict__ W_in, const float* __restrict__ W_h,
    const float* __restrict__ hidden,
    u16* __restrict__ Win_bf, u16* __restrict__ Wh_bf, u16* __restrict__ hid_bf,
    float* __restrict__ out_hidden)
{
    int idx = blockIdx.x * 256 + threadIdx.x;   // 0 .. 1703935
    if (idx < 524288) {
        Win_bf[idx] = f2bf(W_in[idx]);
    } else if (idx < 1572864) {
        int i = idx - 524288;
        Wh_bf[i] = f2bf(W_h[i]);
    } else {
        int i = idx - 1572864;                  // 0 .. 131071
        float h = hidden[i];
        hid_bf[i] = f2bf(h);
        out_hidden[i] = h;                      // second tuple output: hidden
    }
}

// ---------------------------------------------------------------------------
// Kernel 2: bias2[b][h] = hidden @ W_h^T + b_h + b_in   (128 x 1024, K=1024)
// ---------------------------------------------------------------------------
__global__ __launch_bounds__(256, 2) void k_bias2(
    const u16* __restrict__ hid_bf, const u16* __restrict__ Wh_bf,
    const float* __restrict__ b_in, const float* __restrict__ b_h,
    float* __restrict__ bias2)
{
    __shared__ alignas(16) char lds[16384];     // A: [0,8192) B: [8192,16384)
    const int tid = threadIdx.x;
    const int mt = blockIdx.x & 1, nt = blockIdx.x >> 1;   // 2 x 16 tiles
    const int m0 = mt * 64, n0 = nt * 64;
    const int l = tid & 63, w = tid >> 6;
    const int wm = w >> 1, wn = w & 1;
    const int r = l & 15, q = l >> 4;

    f32x4 acc[2][2] = {};

    for (int kb = 0; kb < 1024; kb += 64) {
        __syncthreads();
        #pragma unroll
        for (int i = 0; i < 2; ++i) {
            int idx = tid + i * 256;            // 0..511 : 64 rows x 8 chunks
            int row = idx >> 3, koff = (idx & 7) * 8;
            int off = (row * 128 + koff * 2) ^ ((row & 7) << 4);
            bf16x8 av = *reinterpret_cast<const bf16x8*>(&hid_bf[(m0 + row) * 1024 + kb + koff]);
            *reinterpret_cast<bf16x8*>(&lds[off]) = av;
            bf16x8 bv = *reinterpret_cast<const bf16x8*>(&Wh_bf[(n0 + row) * 1024 + kb + koff]);
            *reinterpret_cast<bf16x8*>(&lds[8192 + off]) = bv;
        }
        __syncthreads();
        #pragma unroll
        for (int kk = 0; kk < 2; ++kk) {
            bf16x8 a[2], b[2];
            #pragma unroll
            for (int mi = 0; mi < 2; ++mi) {
                int row = wm * 32 + mi * 16 + r;
                int off = (row * 128 + kk * 64 + q * 16) ^ ((row & 7) << 4);
                a[mi] = *reinterpret_cast<const bf16x8*>(&lds[off]);
            }
            #pragma unroll
            for (int ni = 0; ni < 2; ++ni) {
                int row = wn * 32 + ni * 16 + r;
                int off = 8192 + ((row * 128 + kk * 64 + q * 16) ^ ((row & 7) << 4));
                b[ni] = *reinterpret_cast<const bf16x8*>(&lds[off]);
            }
            #pragma unroll
            for (int mi = 0; mi < 2; ++mi)
                #pragma unroll
                for (int ni = 0; ni < 2; ++ni)
                    acc[mi][ni] = __builtin_amdgcn_mfma_f32_16x16x32_bf16(
                        a[mi], b[ni], acc[mi][ni], 0, 0, 0);
        }
    }
    #pragma unroll
    for (int mi = 0; mi < 2; ++mi)
        #pragma unroll
        for (int ni = 0; ni < 2; ++ni)
            #pragma unroll
            for (int reg = 0; reg < 4; ++reg) {
                int brow = m0 + wm * 32 + mi * 16 + q * 4 + reg;
                int col  = n0 + wn * 32 + ni * 16 + r;
                bias2[brow * 1024 + col] = acc[mi][ni][reg] + b_in[col] + b_h[col];
            }
}

// ---------------------------------------------------------------------------
// Kernel 3: main GEMM with XCD-bijective swizzle + pipelined staging.
//   A (x, f32): T14 async split — issue loads for k+1 before compute(k),
//               cvt+ds_write after post-compute barrier. Single LDS buffer.
//   B (W_in, bf16): global_load_lds (16B), double-buffered, pre-swizzled src.
//   Raw s_barrier + counted vmcnt(12): in-order vmem completion means
//   "<=12 outstanding" == "4 oldest (= B(k)) landed".
// ---------------------------------------------------------------------------
__global__ __launch_bounds__(256, 3) void k_main(
    const float* __restrict__ x,          // [65536][512] f32
    const u16*   __restrict__ Win_bf,     // [1024][512] bf16
    const float* __restrict__ bias2,      // [128][1024]
    const float* __restrict__ hidden,     // [128][1024]
    float* __restrict__ out)              // [65536][1024]
{
    __shared__ alignas(16) char ldsA[16384];       // 128 rows x 64 bf16, swizzled
    __shared__ alignas(16) char ldsB[2][16384];    // dbuf

    const int tid = threadIdx.x;
    const int bid = (int)blockIdx.x;
    // XCD-bijective swizzle: 4096 % 8 == 0; XCD x owns wgid [x*512, (x+1)*512)
    const int wgid = (bid & 7) * 512 + (bid >> 3);
    const int nt = wgid & 7, mt = wgid >> 3;
    const int m0 = mt * 128, n0 = nt * 128;
    const int l = tid & 63, w = tid >> 6;
    const int wm = w >> 1, wn = w & 1;
    const int r = l & 15, q = l >> 4;

    // B gload addressing: wave w handles segs w*4..w*4+3 (8 rows x 8 chunks each)
    const int brow_in_seg = l >> 3;
    const int bchunk = (l & 7) ^ brow_in_seg;      // pre-swizzled source chunk

    // A staging assignments: idx = tid + i*256 -> row 0..127, chunk 0..7
    int arow[4], achk[4];
    #pragma unroll
    for (int i = 0; i < 4; ++i) { int idx = tid + i * 256; arow[i] = idx >> 3; achk[i] = idx & 7; }

    f32x4 acc[4][4] = {};
    float4 xr[8];

    // ---------------- prologue: stage k=0 ----------------
    #pragma unroll
    for (int i = 0; i < 4; ++i) {
        const float* s = &x[(size_t)(m0 + arow[i]) * 512 + achk[i] * 8];
        xr[2 * i]     = *reinterpret_cast<const float4*>(s);
        xr[2 * i + 1] = *reinterpret_cast<const float4*>(s + 4);
    }
    #pragma unroll
    for (int j = 0; j < 4; ++j) {
        const int seg = w * 4 + j;
        const int row = seg * 8 + brow_in_seg;
        gload_lds16(&Win_bf[(size_t)(n0 + row) * 512 + bchunk * 8],
                    &ldsB[0][seg * 1024]);
    }
    #pragma unroll
    for (int i = 0; i < 4; ++i) {
        union { bf16x8 v; u16 s[8]; } u;
        u.s[0] = f2bf(xr[2*i].x);   u.s[1] = f2bf(xr[2*i].y);
        u.s[2] = f2bf(xr[2*i].z);   u.s[3] = f2bf(xr[2*i].w);
        u.s[4] = f2bf(xr[2*i+1].x); u.s[5] = f2bf(xr[2*i+1].y);
        u.s[6] = f2bf(xr[2*i+1].z); u.s[7] = f2bf(xr[2*i+1].w);
        int off = (arow[i] * 128 + achk[i] * 16) ^ ((arow[i] & 7) << 4);
        *reinterpret_cast<bf16x8*>(&ldsA[off]) = u.v;
    }

    // ---------------- main loop: 8 K-steps of 64 ----------------
    #pragma unroll
    for (int k = 0; k < 8; ++k) {
        if (k < 7) {
            // issue x(k+1) f32 loads (HBM, long latency) and B(k+1) gload_lds
            #pragma unroll
            for (int i = 0; i < 4; ++i) {
                const float* s = &x[(size_t)(m0 + arow[i]) * 512 + (k + 1) * 64 + achk[i] * 8];
                xr[2 * i]     = *reinterpret_cast<const float4*>(s);
                xr[2 * i + 1] = *reinterpret_cast<const float4*>(s + 4);
            }
            #pragma unroll
            for (int j = 0; j < 4; ++j) {
                const int seg = w * 4 + j;
                const int row = seg * 8 + brow_in_seg;
                gload_lds16(&Win_bf[(size_t)(n0 + row) * 512 + (k + 1) * 64 + bchunk * 8],
                            &ldsB[(k + 1) & 1][seg * 1024]);
            }
            // drain B(k) (the <=4 oldest) + own A ds_writes; keep k+1 in flight
            asm volatile("s_waitcnt vmcnt(12) lgkmcnt(0)" ::: "memory");
        } else {
            asm volatile("s_waitcnt vmcnt(0) lgkmcnt(0)" ::: "memory");
        }
        __builtin_amdgcn_s_barrier();
        __builtin_amdgcn_sched_barrier(0);

        // ---- compute K-step k ----
        #pragma unroll
        for (int kk = 0; kk < 2; ++kk) {
            bf16x8 a[4], b[4];
            #pragma unroll
            for (int mi = 0; mi < 4; ++mi) {
                int row = wm * 64 + mi * 16 + r;
                int off = (row * 128 + kk * 64 + q * 16) ^ ((row & 7) << 4);
                a[mi] = *reinterpret_cast<const bf16x8*>(&ldsA[off]);
            }
            #pragma unroll
            for (int ni = 0; ni < 4; ++ni) {
                int row = wn * 64 + ni * 16 + r;
                int off = (row * 128 + kk * 64 + q * 16) ^ ((row & 7) << 4);
                b[ni] = *reinterpret_cast<const bf16x8*>(&ldsB[k & 1][off]);
            }
            #pragma unroll
            for (int mi = 0; mi < 4; ++mi)
                #pragma unroll
                for (int ni = 0; ni < 4; ++ni)
                    acc[mi][ni] = __builtin_amdgcn_mfma_f32_16x16x32_bf16(
                        a[mi], b[ni], acc[mi][ni], 0, 0, 0);
        }

        __builtin_amdgcn_sched_barrier(0);
        __builtin_amdgcn_s_barrier();

        if (k < 7) {
            // cvt + write A(k+1) (implicit vmcnt wait on xr; drains B(k+1) too)
            #pragma unroll
            for (int i = 0; i < 4; ++i) {
                union { bf16x8 v; u16 s[8]; } u;
                u.s[0] = f2bf(xr[2*i].x);   u.s[1] = f2bf(xr[2*i].y);
                u.s[2] = f2bf(xr[2*i].z);   u.s[3] = f2bf(xr[2*i].w);
                u.s[4] = f2bf(xr[2*i+1].x); u.s[5] = f2bf(xr[2*i+1].y);
                u.s[6] = f2bf(xr[2*i+1].z); u.s[7] = f2bf(xr[2*i+1].w);
                int off = (arow[i] * 128 + achk[i] * 16) ^ ((arow[i] & 7) << 4);
                *reinterpret_cast<bf16x8*>(&ldsA[off]) = u.v;
            }
        }
    }

    // ---------------- epilogue ----------------
    #pragma unroll
    for (int mi = 0; mi < 4; ++mi) {
        #pragma unroll
        for (int reg = 0; reg < 4; ++reg) {
            int grow = m0 + wm * 64 + mi * 16 + q * 4 + reg;
            int b = grow & 127;               // m = t*128 + b
            #pragma unroll
            for (int ni = 0; ni < 4; ++ni) {
                int col = n0 + wn * 64 + ni * 16 + r;
                float pre = acc[mi][ni][reg] + bias2[b * 1024 + col];
                float val = 0.1f * fmaxf(pre, 0.0f) + 0.9f * hidden[b * 1024 + col];
                out[(size_t)grow * 1024 + col] = val;
            }
        }
    }
}

// ---------------------------------------------------------------------------
extern "C" void kernel_launch(void* const* d_in, const int* in_sizes, int n_in,
                              void* d_out, int out_size, void* d_ws, size_t ws_size,
                              hipStream_t stream) {
    const float* x      = (const float*)d_in[0];
    const float* hidden = (const float*)d_in[1];
    const float* W_in   = (const float*)d_in[2];
    const float* b_in   = (const float*)d_in[3];
    const float* W_h    = (const float*)d_in[4];
    const float* b_h    = (const float*)d_in[5];
    float* out = (float*)d_out;

    char* ws = (char*)d_ws;
    u16*   Win_bf = (u16*)  (ws + 0);          // 1 MiB
    u16*   Wh_bf  = (u16*)  (ws + 1048576);    // 2 MiB
    u16*   hid_bf = (u16*)  (ws + 3145728);    // 256 KiB
    float* bias2  = (float*)(ws + 3407872);    // 512 KiB

    float* out_hidden = out + OUT_ELEMS;       // tuple output 1: hidden

    k_convert<<<6656, 256, 0, stream>>>(W_in, W_h, hidden, Win_bf, Wh_bf, hid_bf, out_hidden);
    k_bias2<<<32, 256, 0, stream>>>(hid_bf, Wh_bf, b_in, b_h, bias2);
    k_main<<<4096, 256, 0, stream>>>(x, Win_bf, bias2, hidden, out);
}